// Round 7
// baseline (223.482 us; speedup 1.0000x reference)
//
#include <hip/hip_runtime.h>

// Problem constants
#define BQ   2
#define SQ   2048
#define DIMQ 1024
#define HQ   16
#define HDQ  64
#define KQ   64
#define QKV_STRIDE (3 * DIMQ)

typedef __attribute__((ext_vector_type(8))) short short8;   // 8 bf16 (4 VGPRs)
typedef __attribute__((ext_vector_type(4))) float floatx4;  // 4 fp32 acc

typedef const __attribute__((address_space(1))) unsigned short* gas_t;
typedef __attribute__((address_space(3))) unsigned short* las_t;

__device__ __forceinline__ unsigned short f2b(float f) {
    union { float f; unsigned int u; } x; x.f = f;
    unsigned int r = x.u + 0x7fffu + ((x.u >> 16) & 1u);   // RNE
    return (unsigned short)(r >> 16);
}
__device__ __forceinline__ float b2f(unsigned short u) {
    union { unsigned int u; float f; } x; x.u = ((unsigned int)u) << 16;
    return x.f;
}

// ---------------------------------------------------------------------------
// Fused fp32 -> bf16 cast over three buffers (x, w_qkv, w_out), float4 lanes.
__global__ __launch_bounds__(256) void cast3_f32_bf16(const float* __restrict__ s0, unsigned short* __restrict__ d0, int n0,
                                                      const float* __restrict__ s1, unsigned short* __restrict__ d1, int n1,
                                                      const float* __restrict__ s2, unsigned short* __restrict__ d2, int n2) {
    int i = blockIdx.x * blockDim.x + threadIdx.x;
    const float* s; unsigned short* d;
    if (i < n0)                { s = s0; d = d0; }
    else if (i < n0 + n1)      { s = s1; d = d1; i -= n0; }
    else if (i < n0 + n1 + n2) { s = s2; d = d2; i -= n0 + n1; }
    else return;
    float4 v = ((const float4*)s)[i];
    ushort4 o;
    o.x = f2b(v.x); o.y = f2b(v.y); o.z = f2b(v.z); o.w = f2b(v.w);
    ((ushort4*)d)[i] = o;
}

// ---------------------------------------------------------------------------
// C[M,N] = A[M,K] @ B[N,K]^T + bias[N]   (A,B bf16 row-major; C fp32 or bf16)
// BMxBN tile, BK=32, 256 threads = 4 waves (2x2 of BM/2 x BN/2), 16x16x32 MFMA.
template <int BM, int BN, typename CT>
__global__ __launch_bounds__(256) void gemm_bf16_nt(const unsigned short* __restrict__ A,
                                                    const unsigned short* __restrict__ B,
                                                    const float* __restrict__ bias,
                                                    CT* __restrict__ C,
                                                    int M, int N, int K) {
    constexpr int MI = BM / 32;          // mfma tiles per wave (rows)
    constexpr int NJ = BN / 32;          // mfma tiles per wave (cols)
    __shared__ unsigned short As[BM * 32];
    __shared__ unsigned short Bs[BN * 32];

    const int tid  = threadIdx.x;
    const int lane = tid & 63;
    const int wv   = tid >> 6;            // 0..3
    const int wm   = (wv >> 1) * (BM / 2);
    const int wn   = (wv & 1) * (BN / 2);
    const int fr   = lane & 15;           // fragment row (m or n)
    const int fq   = lane >> 4;           // quad -> k segment (8 elems)

    const int m0 = blockIdx.y * BM;
    const int n0 = blockIdx.x * BN;

    floatx4 acc[MI][NJ];
#pragma unroll
    for (int i = 0; i < MI; ++i)
#pragma unroll
        for (int j = 0; j < NJ; ++j) acc[i][j] = (floatx4)(0.f);

    const unsigned short* Ab = A + (size_t)m0 * K;
    const unsigned short* Bb = B + (size_t)n0 * K;

    for (int k0 = 0; k0 < K; k0 += 32) {
#pragma unroll
        for (int c = 0; c < (BM + BN) * 4; c += 256) {
            const int cc = c + tid;
            if (cc < BM * 4) {
                __builtin_amdgcn_global_load_lds(
                    (gas_t)(Ab + (size_t)(cc >> 2) * K + k0 + ((cc & 3) << 3)),
                    (las_t)&As[cc * 8], 16, 0, 0);
            } else {
                const int c2 = cc - BM * 4;
                __builtin_amdgcn_global_load_lds(
                    (gas_t)(Bb + (size_t)(c2 >> 2) * K + k0 + ((c2 & 3) << 3)),
                    (las_t)&Bs[c2 * 8], 16, 0, 0);
            }
        }
        __syncthreads();

        short8 af[MI], bf[NJ];
#pragma unroll
        for (int i = 0; i < MI; ++i)
            af[i] = *(const short8*)&As[(wm + i * 16 + fr) * 32 + fq * 8];
#pragma unroll
        for (int j = 0; j < NJ; ++j)
            bf[j] = *(const short8*)&Bs[(wn + j * 16 + fr) * 32 + fq * 8];
#pragma unroll
        for (int i = 0; i < MI; ++i)
#pragma unroll
            for (int j = 0; j < NJ; ++j)
                acc[i][j] = __builtin_amdgcn_mfma_f32_16x16x32_bf16(af[i], bf[j], acc[i][j], 0, 0, 0);
        __syncthreads();
    }

    // Epilogue. D mapping: col = lane&15 (=fr), row = (lane>>4)*4 + reg (=fq*4+r)
    float bv[NJ];
#pragma unroll
    for (int j = 0; j < NJ; ++j) bv[j] = bias[n0 + wn + j * 16 + fr];
#pragma unroll
    for (int i = 0; i < MI; ++i) {
#pragma unroll
        for (int r = 0; r < 4; ++r) {
            const size_t row = (size_t)(m0 + wm + i * 16 + fq * 4 + r);
#pragma unroll
            for (int j = 0; j < NJ; ++j) {
                const float v = acc[i][j][r] + bv[j];
                if constexpr (sizeof(CT) == 2)
                    C[row * N + n0 + wn + j * 16 + fr] = (CT)f2b(v);
                else
                    C[row * N + n0 + wn + j * 16 + fr] = (CT)v;
            }
        }
    }
}

// ---------------------------------------------------------------------------
// One block per (b,q); 256 threads = 4 waves.
// Phase 1 (MFMA scores): S[64j x 16h] = Kg[64j x 1024] @ Qdiag[1024 x 16h].
//   Wave wv owns j-tile wv*16..+16. A-fragments load DIRECTLY from global:
//   lane (m=lane&15 -> route, kh=lane>>4) reads 16 B of its routed K row.
//   B-fragments: Q (2 KB in LDS) broadcast-read + cndmask to zero lanes whose
//   n (=lane&15) != current head. 2 mfmas per head (64 dims = 2 k-chunks).
// Softmax: verified 16-heads-per-4-waves section, pre-normalized probs.
// Phase 2 (VALU PV): g=t>>7, h=(t&127)>>3, d0=(t&7)*8; plain weighted sum,
//   partial merge across the two j-groups via LDS.
// qkv: bf16 [B, S, 3, H, HD]. out: bf16 [B, S, H*HD].
__global__ __launch_bounds__(256) void attn_kernel(const unsigned short* __restrict__ qkv,
                                                   const int* __restrict__ routes,
                                                   unsigned short* __restrict__ out) {
    __shared__ unsigned short q_lds[DIMQ];   // 2 KB staged Q row (bf16)
    __shared__ int   r_s[KQ];
    __shared__ float s_s[HQ][KQ + 1];        // scores -> normalized probs
    __shared__ float o_part[8][128];         // PV partial merge

    const int t    = threadIdx.x;            // 0..255
    const int lane = t & 63;
    const int wv   = t >> 6;                 // wave 0..3
    const int id   = blockIdx.x;
    // XCD-contiguity swizzle: same XCD (id%8) gets a contiguous bq range.
    const int bq = (id & 7) * 512 + (id >> 3);
    const int b  = bq >> 11;
    const int q  = bq & 2047;

    // Stage Q row (1024 ushorts = 2 KB) via global_load_lds: waves 0,1 cover
    // 512 ushorts each (64 lanes x 16 B). LDS dest = base + lane*16 B.
    if (wv < 2) {
        __builtin_amdgcn_global_load_lds(
            (gas_t)(qkv + (size_t)bq * 3 * DIMQ + wv * 512 + lane * 8),
            (las_t)&q_lds[wv * 512], 16, 0, 0);
    }
    if (t < KQ) r_s[t] = routes[q * KQ + t];
    __syncthreads();

    // ---------------- Phase 1: MFMA scores ----------------
    {
        const int fm = lane & 15;            // m: j within wave tile / n: head col
        const int kh = lane >> 4;            // k-quad (8 elems)
        const int rA = r_s[wv * 16 + fm];    // per-lane route (wave's 16 routes)
        const unsigned short* Abase =
            qkv + ((size_t)b * SQ * 3 + 1) * DIMQ + (size_t)rA * QKV_STRIDE + kh * 8;
        const unsigned short* qbase = &q_lds[kh * 8];

        floatx4 accS = (floatx4)(0.f);
        const short8 z8 = (short8)0;
#pragma unroll
        for (int hh = 0; hh < HQ; ++hh) {
            // A: two adjacent 16 B pieces -> one 128 B line per routed row.
            const short8 a0 = *(const short8*)(Abase + hh * 64);
            const short8 a1 = *(const short8*)(Abase + hh * 64 + 32);
            // B: broadcast Q slice, zeroed unless this lane's head col == hh.
            short8 b0 = *(const short8*)(qbase + hh * 64);
            short8 b1 = *(const short8*)(qbase + hh * 64 + 32);
            if (fm != hh) { b0 = z8; b1 = z8; }
            accS = __builtin_amdgcn_mfma_f32_16x16x32_bf16(a0, b0, accS, 0, 0, 0);
            accS = __builtin_amdgcn_mfma_f32_16x16x32_bf16(a1, b1, accS, 0, 0, 0);
        }
        // D layout: col(h) = lane&15 = fm, row(j) = kh*4 + r. Scale by 1/sqrt(64).
#pragma unroll
        for (int r = 0; r < 4; ++r)
            s_s[fm][wv * 16 + kh * 4 + r] = accS[r] * 0.125f;
    }
    __syncthreads();

    // ---------------- Softmax (pre-normalized probs) ----------------
    {
        const int sh = ((t >> 6) << 2) + ((t & 63) >> 4);   // head
        const int i  = t & 15;
        float v0 = s_s[sh][i], v1 = s_s[sh][i + 16], v2 = s_s[sh][i + 32], v3 = s_s[sh][i + 48];
        float mx = fmaxf(fmaxf(v0, v1), fmaxf(v2, v3));
        mx = fmaxf(mx, __shfl_xor(mx, 1, 64));
        mx = fmaxf(mx, __shfl_xor(mx, 2, 64));
        mx = fmaxf(mx, __shfl_xor(mx, 4, 64));
        mx = fmaxf(mx, __shfl_xor(mx, 8, 64));
        float e0 = __expf(v0 - mx), e1 = __expf(v1 - mx);
        float e2 = __expf(v2 - mx), e3 = __expf(v3 - mx);
        float sm = e0 + e1 + e2 + e3;
        sm += __shfl_xor(sm, 1, 64);
        sm += __shfl_xor(sm, 2, 64);
        sm += __shfl_xor(sm, 4, 64);
        sm += __shfl_xor(sm, 8, 64);
        const float inv = 1.0f / sm;
        s_s[sh][i]      = e0 * inv;
        s_s[sh][i + 16] = e1 * inv;
        s_s[sh][i + 32] = e2 * inv;
        s_s[sh][i + 48] = e3 * inv;
    }
    __syncthreads();

    // ---------------- Phase 2: VALU PV ----------------
    const int g  = t >> 7;                // j-group: 0 or 1
    const int th = t & 127;
    const int h2 = th >> 3;               // head
    const int d0 = (t & 7) * 8;           // dim offset within head

    const size_t baseV = ((size_t)b * SQ * 3 + 2) * DIMQ + h2 * HDQ + d0;
    float o[8];
#pragma unroll
    for (int e = 0; e < 8; ++e) o[e] = 0.f;

#pragma unroll 4
    for (int jj = 0; jj < KQ / 2; ++jj) {
        const int   j = jj * 2 + g;
        const int   r = r_s[j];
        const float w = s_s[h2][j];
        const short8 v8 = *(const short8*)&qkv[baseV + (size_t)r * QKV_STRIDE];
#pragma unroll
        for (int e = 0; e < 8; ++e) o[e] += w * b2f((unsigned short)v8[e]);
    }

    if (g == 1) {
#pragma unroll
        for (int e = 0; e < 8; ++e) o_part[e][th] = o[e];
    }
    __syncthreads();
    if (g == 0) {
        ushort4 lo, hi;
        lo.x = f2b(o[0] + o_part[0][th]); lo.y = f2b(o[1] + o_part[1][th]);
        lo.z = f2b(o[2] + o_part[2][th]); lo.w = f2b(o[3] + o_part[3][th]);
        hi.x = f2b(o[4] + o_part[4][th]); hi.y = f2b(o[5] + o_part[5][th]);
        hi.z = f2b(o[6] + o_part[6][th]); hi.w = f2b(o[7] + o_part[7][th]);
        ushort4* dst = (ushort4*)&out[(size_t)bq * DIMQ + h2 * HDQ + d0];
        dst[0] = lo; dst[1] = hi;
    }
}

// ---------------------------------------------------------------------------
extern "C" void kernel_launch(void* const* d_in, const int* in_sizes, int n_in,
                              void* d_out, int out_size, void* d_ws, size_t ws_size,
                              hipStream_t stream) {
    const float* x      = (const float*)d_in[0];
    const float* w_qkv  = (const float*)d_in[1];
    const float* b_qkv  = (const float*)d_in[2];
    const float* w_out  = (const float*)d_in[3];
    const float* b_out  = (const float*)d_in[4];
    const int*   routes = (const int*)d_in[5];
    float* out = (float*)d_out;

    // ws layout (bytes): [0,24M) qkv bf16 | [24M,..) xb / attnb (aliased)
    //                    then w_qkv_bf16, w_out_bf16
    char* ws = (char*)d_ws;
    unsigned short* qkvb  = (unsigned short*)ws;                      // 24 MB
    unsigned short* xb    = (unsigned short*)(ws + 25165824);         // 8.4 MB
    unsigned short* attnb = xb;                                       // aliased
    unsigned short* wqb   = (unsigned short*)(ws + 33554432);         // 6.3 MB
    unsigned short* wob   = (unsigned short*)(ws + 39845888);         // 2.1 MB

    const int M = BQ * SQ;   // 4096
    dim3 blk(256);

    // Fused casts (x, w_qkv, w_out), float4 per thread
    {
        const int n0 = M * DIMQ / 4, n1 = 3 * DIMQ * DIMQ / 4, n2 = DIMQ * DIMQ / 4;
        cast3_f32_bf16<<<(n0 + n1 + n2 + 255) / 256, blk, 0, stream>>>(
            x, xb, n0, w_qkv, wqb, n1, w_out, wob, n2);
    }

    // 1) QKV projection -> bf16 qkv [B,S,3,H,HD]
    gemm_bf16_nt<128, 128, unsigned short><<<dim3(3 * DIMQ / 128, M / 128), blk, 0, stream>>>(
        xb, wqb, b_qkv, qkvb, M, 3 * DIMQ, DIMQ);

    // 2) Routed attention: one block per (b,q), MFMA scores + VALU PV
    attn_kernel<<<BQ * SQ, blk, 0, stream>>>(qkvb, routes, attnb);

    // 3) Output projection -> fp32 final output (128x64 tiles: 512 blocks, 2/CU)
    gemm_bf16_nt<128, 64, float><<<dim3(DIMQ / 64, M / 128), blk, 0, stream>>>(
        attnb, wob, b_out, out, M, DIMQ, DIMQ);
}

// Round 8
// 189.455 us; speedup vs baseline: 1.1796x; 1.1796x over previous
//
#include <hip/hip_runtime.h>

// Problem constants
#define BQ   2
#define SQ   2048
#define DIMQ 1024
#define HQ   16
#define HDQ  64
#define KQ   64
#define QKV_STRIDE (3 * DIMQ)

typedef __attribute__((ext_vector_type(8))) short short8;   // 8 bf16 (4 VGPRs)
typedef __attribute__((ext_vector_type(4))) float floatx4;  // 4 fp32 acc

typedef const __attribute__((address_space(1))) unsigned short* gas_t;
typedef __attribute__((address_space(3))) unsigned short* las_t;

__device__ __forceinline__ unsigned short f2b(float f) {
    union { float f; unsigned int u; } x; x.f = f;
    unsigned int r = x.u + 0x7fffu + ((x.u >> 16) & 1u);   // RNE
    return (unsigned short)(r >> 16);
}
__device__ __forceinline__ float b2f(unsigned short u) {
    union { unsigned int u; float f; } x; x.u = ((unsigned int)u) << 16;
    return x.f;
}

// ---------------------------------------------------------------------------
// Fused fp32 -> bf16 cast over three buffers (x, w_qkv, w_out), float4 lanes.
__global__ __launch_bounds__(256) void cast3_f32_bf16(const float* __restrict__ s0, unsigned short* __restrict__ d0, int n0,
                                                      const float* __restrict__ s1, unsigned short* __restrict__ d1, int n1,
                                                      const float* __restrict__ s2, unsigned short* __restrict__ d2, int n2) {
    int i = blockIdx.x * blockDim.x + threadIdx.x;
    const float* s; unsigned short* d;
    if (i < n0)                { s = s0; d = d0; }
    else if (i < n0 + n1)      { s = s1; d = d1; i -= n0; }
    else if (i < n0 + n1 + n2) { s = s2; d = d2; i -= n0 + n1; }
    else return;
    float4 v = ((const float4*)s)[i];
    ushort4 o;
    o.x = f2b(v.x); o.y = f2b(v.y); o.z = f2b(v.z); o.w = f2b(v.w);
    ((ushort4*)d)[i] = o;
}

// ---------------------------------------------------------------------------
// C[M,N] = A[M,K] @ B[N,K]^T + bias[N]   (A,B bf16 row-major; C fp32 or bf16)
// BMxBN tile, BK=64 (32 MFMAs between barriers), 256 threads = 4 waves
// (2x2 of BM/2 x BN/2), 16x16x32 MFMA.
// LDS k-chunk XOR swizzle: LDS row-major chunk position p holds global chunk
// p ^ (row&7) — applied on the GLOBAL address during DMA (LDS side must stay
// wave-contiguous for global_load_lds), un-applied at fragment read. Breaks
// the constant-bank-group pattern a 128 B row stride would otherwise have.
template <int BM, int BN, typename CT>
__global__ __launch_bounds__(256) void gemm_bf16_nt(const unsigned short* __restrict__ A,
                                                    const unsigned short* __restrict__ B,
                                                    const float* __restrict__ bias,
                                                    CT* __restrict__ C,
                                                    int M, int N, int K) {
    constexpr int MI = BM / 32;          // 16-row mfma tiles per wave
    constexpr int NJ = BN / 32;          // 16-col mfma tiles per wave
    __shared__ unsigned short As[BM * 64];
    __shared__ unsigned short Bs[BN * 64];

    const int tid  = threadIdx.x;
    const int lane = tid & 63;
    const int wv   = tid >> 6;            // 0..3
    const int wm   = (wv >> 1) * (BM / 2);
    const int wn   = (wv & 1) * (BN / 2);
    const int fr   = lane & 15;           // fragment row (m or n)
    const int fq   = lane >> 4;           // quad -> k segment (8 elems)

    const int m0 = blockIdx.y * BM;
    const int n0 = blockIdx.x * BN;

    floatx4 acc[MI][NJ];
#pragma unroll
    for (int i = 0; i < MI; ++i)
#pragma unroll
        for (int j = 0; j < NJ; ++j) acc[i][j] = (floatx4)(0.f);

    const unsigned short* Ab = A + (size_t)m0 * K;
    const unsigned short* Bb = B + (size_t)n0 * K;

    for (int k0 = 0; k0 < K; k0 += 64) {
        // Stage BM*8 + BN*8 chunks of 16 B. chunk c: row=c>>3, LDS pos=c&7,
        // global k-chunk = (pos ^ (row&7)).
#pragma unroll
        for (int c = 0; c < (BM + BN) * 8; c += 256) {
            const int cc = c + tid;
            if (cc < BM * 8) {
                const int row = cc >> 3;
                const int kc  = ((cc & 7) ^ (row & 7)) << 3;
                __builtin_amdgcn_global_load_lds(
                    (gas_t)(Ab + (size_t)row * K + k0 + kc),
                    (las_t)&As[cc * 8], 16, 0, 0);
            } else {
                const int c2  = cc - BM * 8;
                const int row = c2 >> 3;
                const int kc  = ((c2 & 7) ^ (row & 7)) << 3;
                __builtin_amdgcn_global_load_lds(
                    (gas_t)(Bb + (size_t)row * K + k0 + kc),
                    (las_t)&Bs[c2 * 8], 16, 0, 0);
            }
        }
        __syncthreads();

#pragma unroll
        for (int ks = 0; ks < 2; ++ks) {
            short8 af[MI], bf[NJ];
#pragma unroll
            for (int i = 0; i < MI; ++i) {
                const int row = wm + i * 16 + fr;
                const int pos = (ks * 4 + fq) ^ (row & 7);
                af[i] = *(const short8*)&As[row * 64 + pos * 8];
            }
#pragma unroll
            for (int j = 0; j < NJ; ++j) {
                const int row = wn + j * 16 + fr;
                const int pos = (ks * 4 + fq) ^ (row & 7);
                bf[j] = *(const short8*)&Bs[row * 64 + pos * 8];
            }
#pragma unroll
            for (int i = 0; i < MI; ++i)
#pragma unroll
                for (int j = 0; j < NJ; ++j)
                    acc[i][j] = __builtin_amdgcn_mfma_f32_16x16x32_bf16(af[i], bf[j], acc[i][j], 0, 0, 0);
        }
        __syncthreads();
    }

    // Epilogue. D mapping: col = lane&15 (=fr), row = (lane>>4)*4 + reg (=fq*4+r)
    float bv[NJ];
#pragma unroll
    for (int j = 0; j < NJ; ++j) bv[j] = bias[n0 + wn + j * 16 + fr];
#pragma unroll
    for (int i = 0; i < MI; ++i) {
#pragma unroll
        for (int r = 0; r < 4; ++r) {
            const size_t row = (size_t)(m0 + wm + i * 16 + fq * 4 + r);
#pragma unroll
            for (int j = 0; j < NJ; ++j) {
                const float v = acc[i][j][r] + bv[j];
                if constexpr (sizeof(CT) == 2)
                    C[row * N + n0 + wn + j * 16 + fr] = (CT)f2b(v);
                else
                    C[row * N + n0 + wn + j * 16 + fr] = (CT)v;
            }
        }
    }
}

// ---------------------------------------------------------------------------
// R5's verified attention kernel (60.5 µs, VALU-bound at 82%).
// One block per (b,q); 256 threads; online softmax, single fused gather loop.
// Thread t: j-group g = t>>7, head h = (t&127)>>3, dims d0 = (t&7)*8 (16 B).
// Each iteration gathers one K-row and one V-row (both in flight together).
// qkv: bf16 [B, S, 3, H, HD]. out: bf16 [B, S, H*HD].
__global__ __launch_bounds__(256) void attn_kernel(const unsigned short* __restrict__ qkv,
                                                   const int* __restrict__ routes,
                                                   unsigned short* __restrict__ out) {
    __shared__ int   r_s[KQ];
    __shared__ float m_s[128], l_s[128];
    __shared__ float o_part[8][128];

    const int t  = threadIdx.x;           // 0..255
    const int id = blockIdx.x;
    // XCD-contiguity swizzle: same XCD (id%8) gets a contiguous bq range.
    const int bq = (id & 7) * 512 + (id >> 3);
    const int b  = bq >> 11;
    const int q  = bq & 2047;

    if (t < KQ) r_s[t] = routes[q * KQ + t];

    const int g  = t >> 7;                // j-group: 0 or 1
    const int th = t & 127;
    const int h  = th >> 3;               // head
    const int d0 = (t & 7) * 8;           // dim offset within head

    float qf[8];
    {
        const short8 q8 = *(const short8*)&qkv[((size_t)bq * 3) * DIMQ + h * HDQ + d0];
#pragma unroll
        for (int e = 0; e < 8; ++e) qf[e] = b2f((unsigned short)q8[e]);
    }
    __syncthreads();

    const size_t baseK = ((size_t)b * SQ * 3 + 1) * DIMQ + h * HDQ + d0;
    const size_t baseV = ((size_t)b * SQ * 3 + 2) * DIMQ + h * HDQ + d0;

    float m = -1e30f, l = 0.f;
    float o[8];
#pragma unroll
    for (int e = 0; e < 8; ++e) o[e] = 0.f;

#pragma unroll 4
    for (int jj = 0; jj < KQ / 2; ++jj) {
        const int j = jj * 2 + g;
        const size_t roff = (size_t)r_s[j] * QKV_STRIDE;
        const short8 k8 = *(const short8*)&qkv[baseK + roff];
        const short8 v8 = *(const short8*)&qkv[baseV + roff];
        float p = 0.f;
#pragma unroll
        for (int e = 0; e < 8; ++e) p += qf[e] * b2f((unsigned short)k8[e]);
        p += __shfl_xor(p, 1, 64);
        p += __shfl_xor(p, 2, 64);
        p += __shfl_xor(p, 4, 64);
        const float s  = p * 0.125f;
        const float mn = fmaxf(m, s);
        const float al = __expf(m - mn);
        const float pe = __expf(s - mn);
        l = l * al + pe;
#pragma unroll
        for (int e = 0; e < 8; ++e) o[e] = o[e] * al + pe * b2f((unsigned short)v8[e]);
        m = mn;
    }

    // Merge the two j-groups (online-softmax state merge), then store.
    if (g == 1) {
        m_s[th] = m; l_s[th] = l;
#pragma unroll
        for (int e = 0; e < 8; ++e) o_part[e][th] = o[e];
    }
    __syncthreads();
    if (g == 0) {
        const float m1 = m_s[th], l1 = l_s[th];
        const float mm = fmaxf(m, m1);
        const float a0 = __expf(m - mm);
        const float a1 = __expf(m1 - mm);
        const float inv = 1.0f / (l * a0 + l1 * a1);
        float oo[8];
#pragma unroll
        for (int e = 0; e < 8; ++e) oo[e] = (o[e] * a0 + o_part[e][th] * a1) * inv;
        ushort4 lo, hi;
        lo.x = f2b(oo[0]); lo.y = f2b(oo[1]); lo.z = f2b(oo[2]); lo.w = f2b(oo[3]);
        hi.x = f2b(oo[4]); hi.y = f2b(oo[5]); hi.z = f2b(oo[6]); hi.w = f2b(oo[7]);
        ushort4* dst = (ushort4*)&out[(size_t)bq * DIMQ + h * HDQ + d0];
        dst[0] = lo; dst[1] = hi;
    }
}

// ---------------------------------------------------------------------------
extern "C" void kernel_launch(void* const* d_in, const int* in_sizes, int n_in,
                              void* d_out, int out_size, void* d_ws, size_t ws_size,
                              hipStream_t stream) {
    const float* x      = (const float*)d_in[0];
    const float* w_qkv  = (const float*)d_in[1];
    const float* b_qkv  = (const float*)d_in[2];
    const float* w_out  = (const float*)d_in[3];
    const float* b_out  = (const float*)d_in[4];
    const int*   routes = (const int*)d_in[5];
    float* out = (float*)d_out;

    // ws layout (bytes): [0,24M) qkv bf16 | [24M,..) xb / attnb (aliased)
    //                    then w_qkv_bf16, w_out_bf16
    char* ws = (char*)d_ws;
    unsigned short* qkvb  = (unsigned short*)ws;                      // 24 MB
    unsigned short* xb    = (unsigned short*)(ws + 25165824);         // 8.4 MB
    unsigned short* attnb = xb;                                       // aliased
    unsigned short* wqb   = (unsigned short*)(ws + 33554432);         // 6.3 MB
    unsigned short* wob   = (unsigned short*)(ws + 39845888);         // 2.1 MB

    const int M = BQ * SQ;   // 4096
    dim3 blk(256);

    // Fused casts (x, w_qkv, w_out), float4 per thread
    {
        const int n0 = M * DIMQ / 4, n1 = 3 * DIMQ * DIMQ / 4, n2 = DIMQ * DIMQ / 4;
        cast3_f32_bf16<<<(n0 + n1 + n2 + 255) / 256, blk, 0, stream>>>(
            x, xb, n0, w_qkv, wqb, n1, w_out, wob, n2);
    }

    // 1) QKV projection -> bf16 qkv [B,S,3,H,HD]  (BK=64, 32 MFMAs/barrier)
    gemm_bf16_nt<128, 128, unsigned short><<<dim3(3 * DIMQ / 128, M / 128), blk, 0, stream>>>(
        xb, wqb, b_qkv, qkvb, M, 3 * DIMQ, DIMQ);

    // 2) Routed attention: R5's fused online-softmax kernel
    attn_kernel<<<BQ * SQ, blk, 0, stream>>>(qkvb, routes, attnb);

    // 3) Output projection -> fp32 final output (128x64 tiles: 512 blocks)
    gemm_bf16_nt<128, 64, float><<<dim3(DIMQ / 64, M / 128), blk, 0, stream>>>(
        attnb, wob, b_out, out, M, DIMQ, DIMQ);
}

// Round 9
// 185.078 us; speedup vs baseline: 1.2075x; 1.0236x over previous
//
#include <hip/hip_runtime.h>

// Problem constants
#define BQ   2
#define SQ   2048
#define DIMQ 1024
#define HQ   16
#define HDQ  64
#define KQ   64
#define QKV_STRIDE (3 * DIMQ)

typedef __attribute__((ext_vector_type(8))) short short8;   // 8 bf16 (4 VGPRs)
typedef __attribute__((ext_vector_type(4))) float floatx4;  // 4 fp32 acc

typedef const __attribute__((address_space(1))) unsigned short* gas_t;
typedef __attribute__((address_space(3))) unsigned short* las_t;

__device__ __forceinline__ unsigned short f2b(float f) {
    union { float f; unsigned int u; } x; x.f = f;
    unsigned int r = x.u + 0x7fffu + ((x.u >> 16) & 1u);   // RNE
    return (unsigned short)(r >> 16);
}
__device__ __forceinline__ float b2f(unsigned short u) {
    union { unsigned int u; float f; } x; x.u = ((unsigned int)u) << 16;
    return x.f;
}

// ---------------------------------------------------------------------------
// Fused fp32 -> bf16 cast over three buffers (x, w_qkv, w_out), float4 lanes.
__global__ __launch_bounds__(256) void cast3_f32_bf16(const float* __restrict__ s0, unsigned short* __restrict__ d0, int n0,
                                                      const float* __restrict__ s1, unsigned short* __restrict__ d1, int n1,
                                                      const float* __restrict__ s2, unsigned short* __restrict__ d2, int n2) {
    int i = blockIdx.x * blockDim.x + threadIdx.x;
    const float* s; unsigned short* d;
    if (i < n0)                { s = s0; d = d0; }
    else if (i < n0 + n1)      { s = s1; d = d1; i -= n0; }
    else if (i < n0 + n1 + n2) { s = s2; d = d2; i -= n0 + n1; }
    else return;
    float4 v = ((const float4*)s)[i];
    ushort4 o;
    o.x = f2b(v.x); o.y = f2b(v.y); o.z = f2b(v.z); o.w = f2b(v.w);
    ((ushort4*)d)[i] = o;
}

// ---------------------------------------------------------------------------
// C[M,N] = A[M,K] @ B[N,K]^T + bias[N]   (A,B bf16 row-major; C fp32 or bf16)
// BMxBN tile, BK=64 (32 MFMAs between barriers), 256 threads = 4 waves
// (2x2 of BM/2 x BN/2), 16x16x32 MFMA. XOR k-chunk swizzle on the global side.
template <int BM, int BN, typename CT>
__global__ __launch_bounds__(256) void gemm_bf16_nt(const unsigned short* __restrict__ A,
                                                    const unsigned short* __restrict__ B,
                                                    const float* __restrict__ bias,
                                                    CT* __restrict__ C,
                                                    int M, int N, int K) {
    constexpr int MI = BM / 32;          // 16-row mfma tiles per wave
    constexpr int NJ = BN / 32;          // 16-col mfma tiles per wave
    __shared__ unsigned short As[BM * 64];
    __shared__ unsigned short Bs[BN * 64];

    const int tid  = threadIdx.x;
    const int lane = tid & 63;
    const int wv   = tid >> 6;            // 0..3
    const int wm   = (wv >> 1) * (BM / 2);
    const int wn   = (wv & 1) * (BN / 2);
    const int fr   = lane & 15;           // fragment row (m or n)
    const int fq   = lane >> 4;           // quad -> k segment (8 elems)

    const int m0 = blockIdx.y * BM;
    const int n0 = blockIdx.x * BN;

    floatx4 acc[MI][NJ];
#pragma unroll
    for (int i = 0; i < MI; ++i)
#pragma unroll
        for (int j = 0; j < NJ; ++j) acc[i][j] = (floatx4)(0.f);

    const unsigned short* Ab = A + (size_t)m0 * K;
    const unsigned short* Bb = B + (size_t)n0 * K;

    for (int k0 = 0; k0 < K; k0 += 64) {
#pragma unroll
        for (int c = 0; c < (BM + BN) * 8; c += 256) {
            const int cc = c + tid;
            if (cc < BM * 8) {
                const int row = cc >> 3;
                const int kc  = ((cc & 7) ^ (row & 7)) << 3;
                __builtin_amdgcn_global_load_lds(
                    (gas_t)(Ab + (size_t)row * K + k0 + kc),
                    (las_t)&As[cc * 8], 16, 0, 0);
            } else {
                const int c2  = cc - BM * 8;
                const int row = c2 >> 3;
                const int kc  = ((c2 & 7) ^ (row & 7)) << 3;
                __builtin_amdgcn_global_load_lds(
                    (gas_t)(Bb + (size_t)row * K + k0 + kc),
                    (las_t)&Bs[c2 * 8], 16, 0, 0);
            }
        }
        __syncthreads();

#pragma unroll
        for (int ks = 0; ks < 2; ++ks) {
            short8 af[MI], bf[NJ];
#pragma unroll
            for (int i = 0; i < MI; ++i) {
                const int row = wm + i * 16 + fr;
                const int pos = (ks * 4 + fq) ^ (row & 7);
                af[i] = *(const short8*)&As[row * 64 + pos * 8];
            }
#pragma unroll
            for (int j = 0; j < NJ; ++j) {
                const int row = wn + j * 16 + fr;
                const int pos = (ks * 4 + fq) ^ (row & 7);
                bf[j] = *(const short8*)&Bs[row * 64 + pos * 8];
            }
#pragma unroll
            for (int i = 0; i < MI; ++i)
#pragma unroll
                for (int j = 0; j < NJ; ++j)
                    acc[i][j] = __builtin_amdgcn_mfma_f32_16x16x32_bf16(af[i], bf[j], acc[i][j], 0, 0, 0);
        }
        __syncthreads();
    }

    // Epilogue. D mapping: col = lane&15 (=fr), row = (lane>>4)*4 + reg (=fq*4+r)
    float bv[NJ];
#pragma unroll
    for (int j = 0; j < NJ; ++j) bv[j] = bias[n0 + wn + j * 16 + fr];
#pragma unroll
    for (int i = 0; i < MI; ++i) {
#pragma unroll
        for (int r = 0; r < 4; ++r) {
            const size_t row = (size_t)(m0 + wm + i * 16 + fq * 4 + r);
#pragma unroll
            for (int j = 0; j < NJ; ++j) {
                const float v = acc[i][j][r] + bv[j];
                if constexpr (sizeof(CT) == 2)
                    C[row * N + n0 + wn + j * 16 + fr] = (CT)f2b(v);
                else
                    C[row * N + n0 + wn + j * 16 + fr] = (CT)v;
            }
        }
    }
}

// ---------------------------------------------------------------------------
// R5 attention + 2-slot rotating prefetch (K/V loads for j+2 issued while
// computing j) to raise per-thread memory-level parallelism.
// One block per (b,q); 256 threads; online softmax, fused gather loop.
// Thread t: j-group g = t>>7, head h = (t&127)>>3, dims d0 = (t&7)*8 (16 B).
// qkv: bf16 [B, S, 3, H, HD]. out: bf16 [B, S, H*HD].
__global__ __launch_bounds__(256) void attn_kernel(const unsigned short* __restrict__ qkv,
                                                   const int* __restrict__ routes,
                                                   unsigned short* __restrict__ out) {
    __shared__ int   r_s[KQ];
    __shared__ float m_s[128], l_s[128];
    __shared__ float o_part[8][128];

    const int t  = threadIdx.x;           // 0..255
    const int id = blockIdx.x;
    // XCD-contiguity swizzle: same XCD (id%8) gets a contiguous bq range.
    const int bq = (id & 7) * 512 + (id >> 3);
    const int b  = bq >> 11;
    const int q  = bq & 2047;

    if (t < KQ) r_s[t] = routes[q * KQ + t];

    const int g  = t >> 7;                // j-group: 0 or 1
    const int th = t & 127;
    const int h  = th >> 3;               // head
    const int d0 = (t & 7) * 8;           // dim offset within head

    float qf[8];
    {
        const short8 q8 = *(const short8*)&qkv[((size_t)bq * 3) * DIMQ + h * HDQ + d0];
#pragma unroll
        for (int e = 0; e < 8; ++e) qf[e] = b2f((unsigned short)q8[e]);
    }
    __syncthreads();

    const unsigned short* baseK = qkv + ((size_t)b * SQ * 3 + 1) * DIMQ + h * HDQ + d0;
    const unsigned short* baseV = qkv + ((size_t)b * SQ * 3 + 2) * DIMQ + h * HDQ + d0;

    float m = -1e30f, l = 0.f;
    float o[8];
#pragma unroll
    for (int e = 0; e < 8; ++e) o[e] = 0.f;

    // Prefetch pipeline: 2 slots, loads for iteration jj+2 issued during jj.
    short8 kb[2], vb[2];
#pragma unroll
    for (int i = 0; i < 2; ++i) {
        const size_t roff = (size_t)r_s[i * 2 + g] * QKV_STRIDE;
        kb[i] = *(const short8*)(baseK + roff);
        vb[i] = *(const short8*)(baseV + roff);
    }

#pragma unroll 8
    for (int jj = 0; jj < KQ / 2; ++jj) {
        const int slot = jj & 1;
        const short8 k8 = kb[slot];
        const short8 v8 = vb[slot];
        if (jj + 2 < KQ / 2) {
            const size_t roff = (size_t)r_s[(jj + 2) * 2 + g] * QKV_STRIDE;
            kb[slot] = *(const short8*)(baseK + roff);
            vb[slot] = *(const short8*)(baseV + roff);
        }
        float p = 0.f;
#pragma unroll
        for (int e = 0; e < 8; ++e) p += qf[e] * b2f((unsigned short)k8[e]);
        p += __shfl_xor(p, 1, 64);
        p += __shfl_xor(p, 2, 64);
        p += __shfl_xor(p, 4, 64);
        const float s  = p * 0.125f;
        const float mn = fmaxf(m, s);
        const float al = __expf(m - mn);
        const float pe = __expf(s - mn);
        l = l * al + pe;
#pragma unroll
        for (int e = 0; e < 8; ++e) o[e] = o[e] * al + pe * b2f((unsigned short)v8[e]);
        m = mn;
    }

    // Merge the two j-groups (online-softmax state merge), then store.
    if (g == 1) {
        m_s[th] = m; l_s[th] = l;
#pragma unroll
        for (int e = 0; e < 8; ++e) o_part[e][th] = o[e];
    }
    __syncthreads();
    if (g == 0) {
        const float m1 = m_s[th], l1 = l_s[th];
        const float mm = fmaxf(m, m1);
        const float a0 = __expf(m - mm);
        const float a1 = __expf(m1 - mm);
        const float inv = 1.0f / (l * a0 + l1 * a1);
        float oo[8];
#pragma unroll
        for (int e = 0; e < 8; ++e) oo[e] = (o[e] * a0 + o_part[e][th] * a1) * inv;
        ushort4 lo, hi;
        lo.x = f2b(oo[0]); lo.y = f2b(oo[1]); lo.z = f2b(oo[2]); lo.w = f2b(oo[3]);
        hi.x = f2b(oo[4]); hi.y = f2b(oo[5]); hi.z = f2b(oo[6]); hi.w = f2b(oo[7]);
        ushort4* dst = (ushort4*)&out[(size_t)bq * DIMQ + h * HDQ + d0];
        dst[0] = lo; dst[1] = hi;
    }
}

// ---------------------------------------------------------------------------
extern "C" void kernel_launch(void* const* d_in, const int* in_sizes, int n_in,
                              void* d_out, int out_size, void* d_ws, size_t ws_size,
                              hipStream_t stream) {
    const float* x      = (const float*)d_in[0];
    const float* w_qkv  = (const float*)d_in[1];
    const float* b_qkv  = (const float*)d_in[2];
    const float* w_out  = (const float*)d_in[3];
    const float* b_out  = (const float*)d_in[4];
    const int*   routes = (const int*)d_in[5];
    float* out = (float*)d_out;

    // ws layout (bytes): [0,24M) qkv bf16 | [24M,..) xb / attnb (aliased)
    //                    then w_qkv_bf16, w_out_bf16
    char* ws = (char*)d_ws;
    unsigned short* qkvb  = (unsigned short*)ws;                      // 24 MB
    unsigned short* xb    = (unsigned short*)(ws + 25165824);         // 8.4 MB
    unsigned short* attnb = xb;                                       // aliased
    unsigned short* wqb   = (unsigned short*)(ws + 33554432);         // 6.3 MB
    unsigned short* wob   = (unsigned short*)(ws + 39845888);         // 2.1 MB

    const int M = BQ * SQ;   // 4096
    dim3 blk(256);

    // Fused casts (x, w_qkv, w_out), float4 per thread
    {
        const int n0 = M * DIMQ / 4, n1 = 3 * DIMQ * DIMQ / 4, n2 = DIMQ * DIMQ / 4;
        cast3_f32_bf16<<<(n0 + n1 + n2 + 255) / 256, blk, 0, stream>>>(
            x, xb, n0, w_qkv, wqb, n1, w_out, wob, n2);
    }

    // 1) QKV projection -> bf16 qkv [B,S,3,H,HD]  (BK=64, 32 MFMAs/barrier)
    gemm_bf16_nt<128, 128, unsigned short><<<dim3(3 * DIMQ / 128, M / 128), blk, 0, stream>>>(
        xb, wqb, b_qkv, qkvb, M, 3 * DIMQ, DIMQ);

    // 2) Routed attention: fused online-softmax + prefetch pipeline
    attn_kernel<<<BQ * SQ, blk, 0, stream>>>(qkvb, routes, attnb);

    // 3) Output projection -> fp32 final output (128x64 tiles: 512 blocks)
    gemm_bf16_nt<128, 64, float><<<dim3(DIMQ / 64, M / 128), blk, 0, stream>>>(
        attnb, wob, b_out, out, M, DIMQ, DIMQ);
}